// Round 3
// baseline (303.888 us; speedup 1.0000x reference)
//
#include <hip/hip_runtime.h>
#include <hip/hip_bf16.h>
#include <math.h>

typedef __bf16 bf16_t;
typedef __bf16 bf16x8 __attribute__((ext_vector_type(8)));
typedef float f32x4 __attribute__((ext_vector_type(4)));

#define LOG2E 1.44269504088896340736f

// async global->LDS DMA, 16B per lane; LDS dest = wave-uniform base + lane*16
#define GL2LDS(g, l)                                                     \
  __builtin_amdgcn_global_load_lds(                                      \
      (const __attribute__((address_space(1))) unsigned int*)(g),        \
      (__attribute__((address_space(3))) unsigned int*)(l), 16, 0, 0)

// raw barrier with compiler memory fence (NO implicit vmcnt drain)
#define BAR() asm volatile("s_barrier" ::: "memory")
#define VMCNT0() asm volatile("s_waitcnt vmcnt(0)" ::: "memory")
#define LGKM0()                                         \
  do {                                                  \
    asm volatile("s_waitcnt lgkmcnt(0)" ::: "memory");  \
    __builtin_amdgcn_sched_barrier(0);                  \
  } while (0)

// ------------- convert f32 -> bf16, 8 elems/thread ------------------------
__global__ __launch_bounds__(256) void convert_f32_bf16(const float* __restrict__ in,
                                                        bf16_t* __restrict__ out) {
  const size_t idx = (size_t)(blockIdx.x * 256 + threadIdx.x) * 8;
  f32x4 a = *(const f32x4*)&in[idx];
  f32x4 b = *(const f32x4*)&in[idx + 4];
  bf16x8 v;
#pragma unroll
  for (int i = 0; i < 4; i++) { v[i] = (bf16_t)a[i]; v[i + 4] = (bf16_t)b[i]; }
  *(bf16x8*)&out[idx] = v;
}

// ------------- transpose+convert: in f32 [R][C] -> out bf16 [C][R] --------
__global__ __launch_bounds__(256) void transpose_f32_bf16(const float* __restrict__ in,
                                                          bf16_t* __restrict__ out,
                                                          int R, int C) {
  __shared__ bf16_t t[64][65];
  const int c0 = blockIdx.x * 64, r0 = blockIdx.y * 64;
  const int tx = threadIdx.x, ty = threadIdx.y;  // 64 x 4
#pragma unroll
  for (int i = 0; i < 16; i++) {
    int r = ty + i * 4;
    t[r][tx] = (bf16_t)in[(size_t)(r0 + r) * C + c0 + tx];
  }
  __syncthreads();
#pragma unroll
  for (int i = 0; i < 16; i++) {
    int r = ty + i * 4;
    out[(size_t)(c0 + r) * R + r0 + tx] = t[tx][r];
  }
}

// ------- 128x256 MFMA GEMM, BK=32, 2buf, 1 barrier/tile, 3 blocks/CU ------
// A bf16 [M][1024], Bt bf16 [N][1024]. 512 thr = 8 waves (2m x 4n),
// wave tile 64x64, acc[4][4]. LDS = 2buf x (A 128x32 + B 256x32) bf16 = 48KB
// -> 3 blocks/CU: cross-block TLP covers lgkm/vmcnt latency (m97/m114
// mechanism) instead of the failed intra-block 8-phase pipelining.
// Swizzle (measured zero-conflict in round 2): LDS row r holds its 4
// 8-elem chunks permuted by XOR ((r>>1)&3); staging pre-applies the same
// permutation to the global source so the DMA dest stays linear.
// Per tile t (one epoch, ONE barrier):
//   STG(buf^1, t+1)  (3 x global_load_lds: A 1, B 2)
//   read af[4], bv[4] (8 x ds_read_b128, conflict-free)
//   lgkmcnt(0); setprio(1); 16 MFMA; setprio(0); vmcnt(0); s_barrier
// Safety: after tile t's barrier no wave reads buf (all lgkm waits done
// pre-barrier), so tile t+1's STG into buf is race-free; vmcnt(0) before
// the barrier guarantees buf^1 fully written before tile t+1 reads it.
// MODE 0: epilogue scatters qkv into Q(pre-scaled)/K [B][H][N][64], Vt [B][H][64][N]
// MODE 1: epilogue adds f32 bias, writes f32 [M][1024]
template <int MODE>
__global__ __launch_bounds__(512, 2) void gemmT(const bf16_t* __restrict__ A,
                                                const bf16_t* __restrict__ Bt,
                                                bf16_t* __restrict__ Qb,
                                                bf16_t* __restrict__ Kb,
                                                bf16_t* __restrict__ Vtb,
                                                const float* __restrict__ bias,
                                                float* __restrict__ Out) {
  constexpr int K = 1024;
  constexpr int NT = K / 32;  // 32 K-tiles
  __shared__ __align__(16) bf16_t As[2][128 * 32];
  __shared__ __align__(16) bf16_t Bs[2][256 * 32];
  const int m0 = blockIdx.y * 128, n0 = blockIdx.x * 256;
  const int tid = threadIdx.x;
  const int w = tid >> 6, l = tid & 63;
  const int lr = l & 15, lq = l >> 4;
  const int wm = w >> 2, wn = w & 3;  // 2 x 4 wave grid, wave tile 64x64

  // staging: chunk q = slot*512 + tid; r = q>>2, LDS pos p = q&3,
  // source chunk = p ^ ((r>>1)&3)  (note (r+128) gives the same XOR)
  const int rs = tid >> 2, ps = tid & 3;
  const int cs = (ps ^ ((rs >> 1) & 3)) * 8;
  const size_t gA  = (size_t)(m0 + rs) * K + cs;
  const size_t gB0 = (size_t)(n0 + rs) * K + cs;
  const size_t gB1 = (size_t)(n0 + rs + 128) * K + cs;
  const int ldsu0 = (w * 64) * 8;  // wave-uniform LDS elem offsets
  const int ldsu1 = (512 + w * 64) * 8;

#define STG(bf_, kt_)                                   \
  do {                                                  \
    const size_t kk_ = (size_t)(kt_) * 32;              \
    GL2LDS(&A[gA + kk_], &As[bf_][ldsu0]);              \
    GL2LDS(&Bt[gB0 + kk_], &Bs[bf_][ldsu0]);            \
    GL2LDS(&Bt[gB1 + kk_], &Bs[bf_][ldsu1]);            \
  } while (0)

  // frag ds_read offsets (elems); row*64B base + swizzled 16B chunk
  int aoff[4], boff[4];
#pragma unroll
  for (int mf = 0; mf < 4; mf++) {
    const int row = wm * 64 + mf * 16 + lr;
    aoff[mf] = row * 32 + ((lq ^ ((row >> 1) & 3)) << 3);
  }
#pragma unroll
  for (int nf = 0; nf < 4; nf++) {
    const int row = wn * 64 + nf * 16 + lr;
    boff[nf] = row * 32 + ((lq ^ ((row >> 1) & 3)) << 3);
  }

  f32x4 acc[4][4] = {};

  STG(0, 0);
  VMCNT0();
  BAR();

  for (int t = 0; t < NT; ++t) {
    const int buf = t & 1;
    if (t + 1 < NT) STG(buf ^ 1, t + 1);
    bf16x8 af[4], bv[4];
#pragma unroll
    for (int mf = 0; mf < 4; mf++)
      af[mf] = *(const bf16x8*)&As[buf][aoff[mf]];
#pragma unroll
    for (int nf = 0; nf < 4; nf++)
      bv[nf] = *(const bf16x8*)&Bs[buf][boff[nf]];
    LGKM0();
    __builtin_amdgcn_s_setprio(1);
#pragma unroll
    for (int mf = 0; mf < 4; mf++)
#pragma unroll
      for (int nf = 0; nf < 4; nf++)
        acc[mf][nf] = __builtin_amdgcn_mfma_f32_16x16x32_bf16(af[mf], bv[nf],
                                                              acc[mf][nf], 0, 0, 0);
    __builtin_amdgcn_s_setprio(0);
    VMCNT0();
    BAR();
  }

#pragma unroll
  for (int mf = 0; mf < 4; mf++)
#pragma unroll
    for (int nf = 0; nf < 4; nf++)
#pragma unroll
      for (int i = 0; i < 4; i++) {
        const int m = m0 + wm * 64 + mf * 16 + lq * 4 + i;  // C/D row=(lane>>4)*4+i
        const int c = n0 + wn * 64 + nf * 16 + lr;          //     col=lane&15
        const float v = acc[mf][nf][i];
        if (MODE == 1) {
          Out[(size_t)m * 1024 + c] = v + bias[c];
        } else {
          const int b = m >> 10, n = m & 1023;
          const int which = c >> 10, cc = c & 1023;
          const int hh = cc >> 6, d = cc & 63;
          const size_t qk = ((size_t)((b * 16 + hh) * 1024 + n)) * 64 + d;
          if (which == 0)
            Qb[qk] = (bf16_t)(v * (0.125f * LOG2E));  // fold softmax scale+log2e
          else if (which == 1)
            Kb[qk] = (bf16_t)v;
          else
            Vtb[((size_t)((b * 16 + hh) * 64 + d)) * 1024 + n] = (bf16_t)v;
        }
      }
}

// ---------------- flash attention v3b: one-pass, no-max softmax -----------
// 1 block = (b, h, 128-query tile); 4 waves x 32 queries (2 m-frags each).
// Q pre-scaled by 0.125*log2e -> p = exp2(s). Rowsum via constant ones
// B-frag MFMA (denominator accumulated in o5, col 0).
#define KVS 68
#define PS  72
__global__ __launch_bounds__(256) void attn128(const bf16_t* __restrict__ Qb,
                                               const bf16_t* __restrict__ Kb,
                                               const bf16_t* __restrict__ Vtb,
                                               bf16_t* __restrict__ Ob) {
  __shared__ __align__(16) bf16_t Ks[2][64 * KVS];
  __shared__ __align__(16) bf16_t Vs[2][64 * KVS];
  __shared__ __align__(16) bf16_t Pl[4 * 32 * PS];
  const int bid = blockIdx.x;
  const int qt = bid & 7, h = (bid >> 3) & 15, b = bid >> 7;
  const bf16_t* Qh = Qb + (size_t)((b * 16 + h) * 1024) * 64;
  const bf16_t* Kh = Kb + (size_t)((b * 16 + h) * 1024) * 64;
  const bf16_t* Vh = Vtb + (size_t)((b * 16 + h) * 64) * 1024;  // [64][1024]
  const int tid = threadIdx.x, w = tid >> 6, l = tid & 63;
  const int lr = l & 15, lq = l >> 4;
  const int q0 = qt * 128 + w * 32;

  bf16x8 onesf;
#pragma unroll
  for (int i = 0; i < 8; i++) onesf[i] = (lr == 0) ? (bf16_t)1.0f : (bf16_t)0.0f;

  const int sr = tid >> 3, sc = tid & 7;

  bf16x8 qf[2][2];
#pragma unroll
  for (int mt = 0; mt < 2; mt++)
#pragma unroll
    for (int ks = 0; ks < 2; ks++)
      qf[mt][ks] = *(const bf16x8*)&Qh[(size_t)(q0 + mt * 16 + lr) * 64 + ks * 32 + lq * 8];

  {  // prologue: stage tile 0
    bf16x8 k0 = *(const bf16x8*)&Kh[(size_t)sr * 64 + sc * 8];
    bf16x8 k1 = *(const bf16x8*)&Kh[(size_t)(sr + 32) * 64 + sc * 8];
    bf16x8 v0 = *(const bf16x8*)&Vh[(size_t)sr * 1024 + sc * 8];
    bf16x8 v1 = *(const bf16x8*)&Vh[(size_t)(sr + 32) * 1024 + sc * 8];
    *(bf16x8*)&Ks[0][sr * KVS + sc * 8] = k0;
    *(bf16x8*)&Ks[0][(sr + 32) * KVS + sc * 8] = k1;
    *(bf16x8*)&Vs[0][sr * KVS + sc * 8] = v0;
    *(bf16x8*)&Vs[0][(sr + 32) * KVS + sc * 8] = v1;
  }
  __syncthreads();

  f32x4 o[2][4] = {};
  f32x4 o5[2] = {};
  bf16_t* pw = &Pl[w * 32 * PS];

  for (int it = 0; it < 16; ++it) {
    const int buf = it & 1;
    bf16x8 nk0, nk1, nv0, nv1;
    if (it < 15) {
      const int jn = (it + 1) * 64;
      nk0 = *(const bf16x8*)&Kh[(size_t)(jn + sr) * 64 + sc * 8];
      nk1 = *(const bf16x8*)&Kh[(size_t)(jn + sr + 32) * 64 + sc * 8];
      nv0 = *(const bf16x8*)&Vh[(size_t)sr * 1024 + jn + sc * 8];
      nv1 = *(const bf16x8*)&Vh[(size_t)(sr + 32) * 1024 + jn + sc * 8];
    }
    f32x4 s[2][4] = {};
#pragma unroll
    for (int ks = 0; ks < 2; ks++)
#pragma unroll
      for (int nt = 0; nt < 4; nt++) {
        bf16x8 kf = *(const bf16x8*)&Ks[buf][(nt * 16 + lr) * KVS + ks * 32 + lq * 8];
#pragma unroll
        for (int mt = 0; mt < 2; mt++)
          s[mt][nt] = __builtin_amdgcn_mfma_f32_16x16x32_bf16(qf[mt][ks], kf, s[mt][nt], 0, 0, 0);
      }
#pragma unroll
    for (int mt = 0; mt < 2; mt++)
#pragma unroll
      for (int nt = 0; nt < 4; nt++)
#pragma unroll
        for (int i = 0; i < 4; i++)
          pw[(mt * 16 + lq * 4 + i) * PS + nt * 16 + lr] = (bf16_t)exp2f(s[mt][nt][i]);
#pragma unroll
    for (int ks = 0; ks < 2; ks++) {
      bf16x8 af[2];
#pragma unroll
      for (int mt = 0; mt < 2; mt++)
        af[mt] = *(const bf16x8*)&pw[(mt * 16 + lr) * PS + ks * 32 + lq * 8];
#pragma unroll
      for (int nt = 0; nt < 4; nt++) {
        bf16x8 vf = *(const bf16x8*)&Vs[buf][(nt * 16 + lr) * KVS + ks * 32 + lq * 8];
#pragma unroll
        for (int mt = 0; mt < 2; mt++)
          o[mt][nt] = __builtin_amdgcn_mfma_f32_16x16x32_bf16(af[mt], vf, o[mt][nt], 0, 0, 0);
      }
#pragma unroll
      for (int mt = 0; mt < 2; mt++)
        o5[mt] = __builtin_amdgcn_mfma_f32_16x16x32_bf16(af[mt], onesf, o5[mt], 0, 0, 0);
    }
    if (it < 15) {
      *(bf16x8*)&Ks[buf ^ 1][sr * KVS + sc * 8] = nk0;
      *(bf16x8*)&Ks[buf ^ 1][(sr + 32) * KVS + sc * 8] = nk1;
      *(bf16x8*)&Vs[buf ^ 1][sr * KVS + sc * 8] = nv0;
      *(bf16x8*)&Vs[buf ^ 1][(sr + 32) * KVS + sc * 8] = nv1;
    }
    __syncthreads();
  }
#pragma unroll
  for (int mt = 0; mt < 2; mt++)
#pragma unroll
    for (int i = 0; i < 4; i++) {
      float lsum = __shfl(o5[mt][i], lq * 16);  // lane (lq,lr=0) holds rowsum
      float inv = 1.0f / lsum;
      int grow = b * 1024 + q0 + mt * 16 + lq * 4 + i;
#pragma unroll
      for (int nt = 0; nt < 4; nt++) {
        int col = h * 64 + nt * 16 + lr;
        Ob[(size_t)grow * 1024 + col] = (bf16_t)(o[mt][nt][i] * inv);
      }
    }
}

extern "C" void kernel_launch(void* const* d_in, const int* in_sizes, int n_in,
                              void* d_out, int out_size, void* d_ws, size_t ws_size,
                              hipStream_t stream) {
  const float* x     = (const float*)d_in[0];  // [8,1024,1024] f32
  const float* w_qkv = (const float*)d_in[1];  // [1024,3072] f32
  const float* w_out = (const float*)d_in[2];  // [1024,1024] f32
  const float* b_out = (const float*)d_in[3];  // [1024] f32
  float* out = (float*)d_out;                  // [8,1024,1024] f32

  bf16_t* ws = (bf16_t*)d_ws;
  const size_t SZ = (size_t)8 * 1024 * 1024;  // elems per 16MB buffer
  bf16_t* Qb  = ws;            // [B][H][N][64]  (pre-scaled)
  bf16_t* Kb  = Qb + SZ;       // [B][H][N][64]
  bf16_t* Vtb = Kb + SZ;       // [B][H][64][N]
  bf16_t* Ob  = Vtb + SZ;      // [B*N][H*64]; also aliases Xb (dead after gemm0)
  bf16_t* Wqt = Ob + SZ;       // [3072][1024]
  bf16_t* Wot = Wqt + (size_t)3072 * 1024;  // [1024][1024]
  bf16_t* Xb  = Ob;            // x as bf16 [8192][1024]
  // total ws use: 72 MB

  hipLaunchKernelGGL(convert_f32_bf16, dim3(4096), dim3(256), 0, stream, x, Xb);
  hipLaunchKernelGGL(transpose_f32_bf16, dim3(48, 16), dim3(64, 4), 0, stream,
                     w_qkv, Wqt, 1024, 3072);
  hipLaunchKernelGGL(transpose_f32_bf16, dim3(16, 16), dim3(64, 4), 0, stream,
                     w_out, Wot, 1024, 1024);
  hipLaunchKernelGGL((gemmT<0>), dim3(12, 64), dim3(512), 0, stream,
                     Xb, Wqt, Qb, Kb, Vtb, (const float*)nullptr, (float*)nullptr);
  hipLaunchKernelGGL(attn128, dim3(1024), dim3(256), 0, stream, Qb, Kb, Vtb, Ob);
  hipLaunchKernelGGL((gemmT<1>), dim3(4, 64), dim3(512), 0, stream,
                     Ob, Wot, (bf16_t*)nullptr, (bf16_t*)nullptr, (bf16_t*)nullptr,
                     b_out, out);
}

// Round 4
// 279.867 us; speedup vs baseline: 1.0858x; 1.0858x over previous
//
#include <hip/hip_runtime.h>
#include <hip/hip_bf16.h>
#include <math.h>

typedef __bf16 bf16_t;
typedef __bf16 bf16x8 __attribute__((ext_vector_type(8)));
typedef float f32x4 __attribute__((ext_vector_type(4)));

#define LOG2E 1.44269504088896340736f

// async global->LDS DMA, 16B per lane; LDS dest = wave-uniform base + lane*16
#define GL2LDS(g, l)                                                     \
  __builtin_amdgcn_global_load_lds(                                      \
      (const __attribute__((address_space(1))) unsigned int*)(g),        \
      (__attribute__((address_space(3))) unsigned int*)(l), 16, 0, 0)

// raw barrier with compiler memory fence (NO implicit vmcnt drain)
#define BAR() asm volatile("s_barrier" ::: "memory")
#define VMCNT(n) asm volatile("s_waitcnt vmcnt(" #n ")" ::: "memory")
#define LGKM0()                                         \
  do {                                                  \
    asm volatile("s_waitcnt lgkmcnt(0)" ::: "memory");  \
    __builtin_amdgcn_sched_barrier(0);                  \
  } while (0)

// ------------- convert f32 -> bf16, 8 elems/thread ------------------------
__global__ __launch_bounds__(256) void convert_f32_bf16(const float* __restrict__ in,
                                                        bf16_t* __restrict__ out) {
  const size_t idx = (size_t)(blockIdx.x * 256 + threadIdx.x) * 8;
  f32x4 a = *(const f32x4*)&in[idx];
  f32x4 b = *(const f32x4*)&in[idx + 4];
  bf16x8 v;
#pragma unroll
  for (int i = 0; i < 4; i++) { v[i] = (bf16_t)a[i]; v[i + 4] = (bf16_t)b[i]; }
  *(bf16x8*)&out[idx] = v;
}

// ------------- transpose+convert: in f32 [R][C] -> out bf16 [C][R] --------
__global__ __launch_bounds__(256) void transpose_f32_bf16(const float* __restrict__ in,
                                                          bf16_t* __restrict__ out,
                                                          int R, int C) {
  __shared__ bf16_t t[64][65];
  const int c0 = blockIdx.x * 64, r0 = blockIdx.y * 64;
  const int tx = threadIdx.x, ty = threadIdx.y;  // 64 x 4
#pragma unroll
  for (int i = 0; i < 16; i++) {
    int r = ty + i * 4;
    t[r][tx] = (bf16_t)in[(size_t)(r0 + r) * C + c0 + tx];
  }
  __syncthreads();
#pragma unroll
  for (int i = 0; i < 16; i++) {
    int r = ty + i * 4;
    out[(size_t)(c0 + r) * R + r0 + tx] = t[tx][r];
  }
}

// ---- 128x128 MFMA GEMM, BK=32, TRIPLE-buffered, counted vmcnt(4) ---------
// Theory (round 3 post-mortem): all prior variants exposed HBM latency
// because the per-tile wait covered loads issued <1 tile earlier. Here the
// prefetch distance is 2: at tile t we stage tile t+2 into buf[(t+2)%3];
// the end-of-tile VMCNT(4) waits only for group t+1 (issued one full tile
// ~800cy ago) and leaves group t+2 in flight -> latency hidden (T4).
// 256 thr = 4 waves (2x2), wave tile 64x64, acc[4][4] = 64 AGPR; target
// total regs <=128 (launch_bounds(256,4)) -> 4 waves/SIMD, LDS 48KB ->
// 3 blocks/CU: many desynced waves to fill remaining stalls.
// Swizzle (round-2-verified zero-conflict): LDS chunk (r,p) holds global
// chunk p ^ ((r>>1)&3); frag read at chunk lq ^ ((row>>1)&3) -> free 2-way.
// Race safety: STG at tile t writes buf[(t-1)%3], whose reads completed
// before the end-of-(t-1) barrier; VMCNT precedes BAR so after the barrier
// every wave's group t+1 data is visible.
// MODE 0: epilogue scatters qkv into Q(pre-scaled)/K [B][H][N][64], Vt [B][H][64][N]
// MODE 1: epilogue adds f32 bias, writes f32 [M][1024]
template <int MODE>
__global__ __launch_bounds__(256, 4) void gemmT(const bf16_t* __restrict__ A,
                                                const bf16_t* __restrict__ Bt,
                                                bf16_t* __restrict__ Qb,
                                                bf16_t* __restrict__ Kb,
                                                bf16_t* __restrict__ Vtb,
                                                const float* __restrict__ bias,
                                                float* __restrict__ Out) {
  constexpr int K = 1024;
  constexpr int NT = K / 32;  // 32 K-tiles
  __shared__ __align__(16) bf16_t As[3][128 * 32];
  __shared__ __align__(16) bf16_t Bs[3][128 * 32];
  // XCD-aware bijective swizzle (grid sizes are multiples of 8)
  const int gx = gridDim.x;
  const int lin = blockIdx.y * gx + blockIdx.x;
  const int per = (gx * gridDim.y) >> 3;
  const int swz = (lin & 7) * per + (lin >> 3);
  const int m0 = (swz / gx) * 128, n0 = (swz % gx) * 128;
  const int tid = threadIdx.x;
  const int w = tid >> 6, l = tid & 63;
  const int lr = l & 15, lq = l >> 4;
  const int wm = w >> 1, wn = w & 1;  // 2 x 2 wave grid, wave tile 64x64

  // staging: chunk c = slot*256 + tid; r = c>>2 = slot*64 + (tid>>2),
  // LDS pos p = c&3, source chunk = p ^ ((r>>1)&3) (slot-invariant: 64/2=32 ≡ 0 mod 4)
  const int rs = tid >> 2, ps = tid & 3;
  const int cs = (ps ^ ((rs >> 1) & 3)) * 8;
  const size_t gA0 = (size_t)(m0 + rs) * K + cs;
  const size_t gA1 = (size_t)(m0 + 64 + rs) * K + cs;
  const size_t gB0 = (size_t)(n0 + rs) * K + cs;
  const size_t gB1 = (size_t)(n0 + 64 + rs) * K + cs;
  const int ldsu0 = (w * 64) * 8;          // wave-uniform LDS elem offsets
  const int ldsu1 = (256 + w * 64) * 8;

#define STG(bf_, kt_)                                   \
  do {                                                  \
    const size_t kk_ = (size_t)(kt_) * 32;              \
    GL2LDS(&A[gA0 + kk_], &As[bf_][ldsu0]);             \
    GL2LDS(&A[gA1 + kk_], &As[bf_][ldsu1]);             \
    GL2LDS(&Bt[gB0 + kk_], &Bs[bf_][ldsu0]);            \
    GL2LDS(&Bt[gB1 + kk_], &Bs[bf_][ldsu1]);            \
  } while (0)

  // frag ds_read offsets (elems); row*64B base + swizzled 16B chunk
  int aoff[4], boff[4];
#pragma unroll
  for (int mf = 0; mf < 4; mf++) {
    const int row = wm * 64 + mf * 16 + lr;
    aoff[mf] = row * 32 + ((lq ^ ((row >> 1) & 3)) << 3);
  }
#pragma unroll
  for (int nf = 0; nf < 4; nf++) {
    const int row = wn * 64 + nf * 16 + lr;
    boff[nf] = row * 32 + ((lq ^ ((row >> 1) & 3)) << 3);
  }

  f32x4 acc[4][4] = {};

  // prologue: stage tiles 0 and 1 (groups of 4 loads each); wait group 0
  STG(0, 0);
  STG(1, 1);
  VMCNT(4);
  BAR();

  for (int t = 0; t < NT; ++t) {
    const int bufR = t % 3;
    if (t + 2 < NT) STG((t + 2) % 3, t + 2);
    bf16x8 af[4], bv[4];
#pragma unroll
    for (int mf = 0; mf < 4; mf++)
      af[mf] = *(const bf16x8*)&As[bufR][aoff[mf]];
#pragma unroll
    for (int nf = 0; nf < 4; nf++)
      bv[nf] = *(const bf16x8*)&Bs[bufR][boff[nf]];
    LGKM0();
    __builtin_amdgcn_s_setprio(1);
#pragma unroll
    for (int mf = 0; mf < 4; mf++)
#pragma unroll
      for (int nf = 0; nf < 4; nf++)
        acc[mf][nf] = __builtin_amdgcn_mfma_f32_16x16x32_bf16(af[mf], bv[nf],
                                                              acc[mf][nf], 0, 0, 0);
    __builtin_amdgcn_s_setprio(0);
    // counted wait: group t+1 must land before the next tile reads it;
    // group t+2 (the 4 newest loads) stays in flight across the barrier.
    if (t == NT - 2) { VMCNT(0); } else if (t < NT - 2) { VMCNT(4); }
    BAR();
  }

#pragma unroll
  for (int mf = 0; mf < 4; mf++)
#pragma unroll
    for (int nf = 0; nf < 4; nf++)
#pragma unroll
      for (int i = 0; i < 4; i++) {
        const int m = m0 + wm * 64 + mf * 16 + lq * 4 + i;  // C/D row=(lane>>4)*4+i
        const int c = n0 + wn * 64 + nf * 16 + lr;          //     col=lane&15
        const float v = acc[mf][nf][i];
        if (MODE == 1) {
          Out[(size_t)m * 1024 + c] = v + bias[c];
        } else {
          const int b = m >> 10, n = m & 1023;
          const int which = c >> 10, cc = c & 1023;
          const int hh = cc >> 6, d = cc & 63;
          const size_t qk = ((size_t)((b * 16 + hh) * 1024 + n)) * 64 + d;
          if (which == 0)
            Qb[qk] = (bf16_t)(v * (0.125f * LOG2E));  // fold softmax scale+log2e
          else if (which == 1)
            Kb[qk] = (bf16_t)v;
          else
            Vtb[((size_t)((b * 16 + hh) * 64 + d)) * 1024 + n] = (bf16_t)v;
        }
      }
}

// ---------------- flash attention v3b: one-pass, no-max softmax -----------
// 1 block = (b, h, 128-query tile); 4 waves x 32 queries (2 m-frags each).
// Q pre-scaled by 0.125*log2e -> p = exp2(s). Rowsum via constant ones
// B-frag MFMA (denominator accumulated in o5, col 0).
#define KVS 68
#define PS  72
__global__ __launch_bounds__(256) void attn128(const bf16_t* __restrict__ Qb,
                                               const bf16_t* __restrict__ Kb,
                                               const bf16_t* __restrict__ Vtb,
                                               bf16_t* __restrict__ Ob) {
  __shared__ __align__(16) bf16_t Ks[2][64 * KVS];
  __shared__ __align__(16) bf16_t Vs[2][64 * KVS];
  __shared__ __align__(16) bf16_t Pl[4 * 32 * PS];
  const int bid = blockIdx.x;
  const int qt = bid & 7, h = (bid >> 3) & 15, b = bid >> 7;
  const bf16_t* Qh = Qb + (size_t)((b * 16 + h) * 1024) * 64;
  const bf16_t* Kh = Kb + (size_t)((b * 16 + h) * 1024) * 64;
  const bf16_t* Vh = Vtb + (size_t)((b * 16 + h) * 64) * 1024;  // [64][1024]
  const int tid = threadIdx.x, w = tid >> 6, l = tid & 63;
  const int lr = l & 15, lq = l >> 4;
  const int q0 = qt * 128 + w * 32;

  bf16x8 onesf;
#pragma unroll
  for (int i = 0; i < 8; i++) onesf[i] = (lr == 0) ? (bf16_t)1.0f : (bf16_t)0.0f;

  const int sr = tid >> 3, sc = tid & 7;

  bf16x8 qf[2][2];
#pragma unroll
  for (int mt = 0; mt < 2; mt++)
#pragma unroll
    for (int ks = 0; ks < 2; ks++)
      qf[mt][ks] = *(const bf16x8*)&Qh[(size_t)(q0 + mt * 16 + lr) * 64 + ks * 32 + lq * 8];

  {  // prologue: stage tile 0
    bf16x8 k0 = *(const bf16x8*)&Kh[(size_t)sr * 64 + sc * 8];
    bf16x8 k1 = *(const bf16x8*)&Kh[(size_t)(sr + 32) * 64 + sc * 8];
    bf16x8 v0 = *(const bf16x8*)&Vh[(size_t)sr * 1024 + sc * 8];
    bf16x8 v1 = *(const bf16x8*)&Vh[(size_t)(sr + 32) * 1024 + sc * 8];
    *(bf16x8*)&Ks[0][sr * KVS + sc * 8] = k0;
    *(bf16x8*)&Ks[0][(sr + 32) * KVS + sc * 8] = k1;
    *(bf16x8*)&Vs[0][sr * KVS + sc * 8] = v0;
    *(bf16x8*)&Vs[0][(sr + 32) * KVS + sc * 8] = v1;
  }
  __syncthreads();

  f32x4 o[2][4] = {};
  f32x4 o5[2] = {};
  bf16_t* pw = &Pl[w * 32 * PS];

  for (int it = 0; it < 16; ++it) {
    const int buf = it & 1;
    bf16x8 nk0, nk1, nv0, nv1;
    if (it < 15) {
      const int jn = (it + 1) * 64;
      nk0 = *(const bf16x8*)&Kh[(size_t)(jn + sr) * 64 + sc * 8];
      nk1 = *(const bf16x8*)&Kh[(size_t)(jn + sr + 32) * 64 + sc * 8];
      nv0 = *(const bf16x8*)&Vh[(size_t)sr * 1024 + jn + sc * 8];
      nv1 = *(const bf16x8*)&Vh[(size_t)(sr + 32) * 1024 + jn + sc * 8];
    }
    f32x4 s[2][4] = {};
#pragma unroll
    for (int ks = 0; ks < 2; ks++)
#pragma unroll
      for (int nt = 0; nt < 4; nt++) {
        bf16x8 kf = *(const bf16x8*)&Ks[buf][(nt * 16 + lr) * KVS + ks * 32 + lq * 8];
#pragma unroll
        for (int mt = 0; mt < 2; mt++)
          s[mt][nt] = __builtin_amdgcn_mfma_f32_16x16x32_bf16(qf[mt][ks], kf, s[mt][nt], 0, 0, 0);
      }
#pragma unroll
    for (int mt = 0; mt < 2; mt++)
#pragma unroll
      for (int nt = 0; nt < 4; nt++)
#pragma unroll
        for (int i = 0; i < 4; i++)
          pw[(mt * 16 + lq * 4 + i) * PS + nt * 16 + lr] = (bf16_t)exp2f(s[mt][nt][i]);
#pragma unroll
    for (int ks = 0; ks < 2; ks++) {
      bf16x8 af[2];
#pragma unroll
      for (int mt = 0; mt < 2; mt++)
        af[mt] = *(const bf16x8*)&pw[(mt * 16 + lr) * PS + ks * 32 + lq * 8];
#pragma unroll
      for (int nt = 0; nt < 4; nt++) {
        bf16x8 vf = *(const bf16x8*)&Vs[buf][(nt * 16 + lr) * KVS + ks * 32 + lq * 8];
#pragma unroll
        for (int mt = 0; mt < 2; mt++)
          o[mt][nt] = __builtin_amdgcn_mfma_f32_16x16x32_bf16(af[mt], vf, o[mt][nt], 0, 0, 0);
      }
#pragma unroll
      for (int mt = 0; mt < 2; mt++)
        o5[mt] = __builtin_amdgcn_mfma_f32_16x16x32_bf16(af[mt], onesf, o5[mt], 0, 0, 0);
    }
    if (it < 15) {
      *(bf16x8*)&Ks[buf ^ 1][sr * KVS + sc * 8] = nk0;
      *(bf16x8*)&Ks[buf ^ 1][(sr + 32) * KVS + sc * 8] = nk1;
      *(bf16x8*)&Vs[buf ^ 1][sr * KVS + sc * 8] = nv0;
      *(bf16x8*)&Vs[buf ^ 1][(sr + 32) * KVS + sc * 8] = nv1;
    }
    __syncthreads();
  }
#pragma unroll
  for (int mt = 0; mt < 2; mt++)
#pragma unroll
    for (int i = 0; i < 4; i++) {
      float lsum = __shfl(o5[mt][i], lq * 16);  // lane (lq,lr=0) holds rowsum
      float inv = 1.0f / lsum;
      int grow = b * 1024 + q0 + mt * 16 + lq * 4 + i;
#pragma unroll
      for (int nt = 0; nt < 4; nt++) {
        int col = h * 64 + nt * 16 + lr;
        Ob[(size_t)grow * 1024 + col] = (bf16_t)(o[mt][nt][i] * inv);
      }
    }
}

extern "C" void kernel_launch(void* const* d_in, const int* in_sizes, int n_in,
                              void* d_out, int out_size, void* d_ws, size_t ws_size,
                              hipStream_t stream) {
  const float* x     = (const float*)d_in[0];  // [8,1024,1024] f32
  const float* w_qkv = (const float*)d_in[1];  // [1024,3072] f32
  const float* w_out = (const float*)d_in[2];  // [1024,1024] f32
  const float* b_out = (const float*)d_in[3];  // [1024] f32
  float* out = (float*)d_out;                  // [8,1024,1024] f32

  bf16_t* ws = (bf16_t*)d_ws;
  const size_t SZ = (size_t)8 * 1024 * 1024;  // elems per 16MB buffer
  bf16_t* Qb  = ws;            // [B][H][N][64]  (pre-scaled)
  bf16_t* Kb  = Qb + SZ;       // [B][H][N][64]
  bf16_t* Vtb = Kb + SZ;       // [B][H][64][N]
  bf16_t* Ob  = Vtb + SZ;      // [B*N][H*64]; also aliases Xb (dead after gemm0)
  bf16_t* Wqt = Ob + SZ;       // [3072][1024]
  bf16_t* Wot = Wqt + (size_t)3072 * 1024;  // [1024][1024]
  bf16_t* Xb  = Ob;            // x as bf16 [8192][1024]
  // total ws use: 72 MB

  hipLaunchKernelGGL(convert_f32_bf16, dim3(4096), dim3(256), 0, stream, x, Xb);
  hipLaunchKernelGGL(transpose_f32_bf16, dim3(48, 16), dim3(64, 4), 0, stream,
                     w_qkv, Wqt, 1024, 3072);
  hipLaunchKernelGGL(transpose_f32_bf16, dim3(16, 16), dim3(64, 4), 0, stream,
                     w_out, Wot, 1024, 1024);
  hipLaunchKernelGGL((gemmT<0>), dim3(24, 64), dim3(256), 0, stream,
                     Xb, Wqt, Qb, Kb, Vtb, (const float*)nullptr, (float*)nullptr);
  hipLaunchKernelGGL(attn128, dim3(1024), dim3(256), 0, stream, Qb, Kb, Vtb, Ob);
  hipLaunchKernelGGL((gemmT<1>), dim3(8, 64), dim3(256), 0, stream,
                     Ob, Wot, (bf16_t*)nullptr, (bf16_t*)nullptr, (bf16_t*)nullptr,
                     b_out, out);
}